// Round 20
// baseline (248.923 us; speedup 1.0000x reference)
//
#include <hip/hip_runtime.h>
#include <hip/hip_fp16.h>

#define NN 50000
#define EE 800000
#define NP 50176        // padded N stride
#define BSH 7           // bucket shift: 128 nodes/bucket
#define NBUK 391        // ((NN-1)>>BSH)+1
#define BCAP 4096       // max edges per bucket held in LDS
#define NBLKA 512       // blocks for hist/partition passes (2/CU)

using f16x8 = __attribute__((ext_vector_type(8))) _Float16;
using f32x4 = __attribute__((ext_vector_type(4))) float;

__device__ inline short4 f4_to_h4(float4 o) {
    union { __half h[4]; short4 s; } u;
    u.h[0] = __float2half_rn(o.x); u.h[1] = __float2half_rn(o.y);
    u.h[2] = __float2half_rn(o.z); u.h[3] = __float2half_rn(o.w);
    return u.s;
}

// ---------------- x fp32 -> fp16 (vectorized, 8/thread) ----------------
__global__ __launch_bounds__(256) void cvt_x_kernel(const float* __restrict__ x,
                                                    __half* __restrict__ xh, int n8) {
    int i = blockIdx.x * 256 + threadIdx.x;
    if (i < n8) {
        float4 v0 = reinterpret_cast<const float4*>(x)[i * 2];
        float4 v1 = reinterpret_cast<const float4*>(x)[i * 2 + 1];
        short4 h0 = f4_to_h4(v0);
        short4 h1 = f4_to_h4(v1);
        reinterpret_cast<short4*>(xh)[i * 2] = h0;
        reinterpret_cast<short4*>(xh)[i * 2 + 1] = h1;
    }
}

// ---------------- bucket histogram (LDS-aggregated) ----------------
__global__ __launch_bounds__(256) void histb_kernel(const int* __restrict__ dst,
                                                    int* __restrict__ bcnt, int E) {
    __shared__ int h[512];
    int t = threadIdx.x;
    h[t] = 0; h[t + 256] = 0;
    __syncthreads();
    int chunk = (E + NBLKA - 1) / NBLKA;
    int beg = blockIdx.x * chunk;
    int end = min(beg + chunk, E);
    for (int e = beg + t; e < end; e += 256) atomicAdd(&h[dst[e] >> BSH], 1);
    __syncthreads();
    if (h[t]) atomicAdd(&bcnt[t], h[t]);
    if (h[t + 256]) atomicAdd(&bcnt[t + 256], h[t + 256]);
}

// ---------------- bucket offset scan (single block, 512 threads) ----------------
__global__ __launch_bounds__(512) void bscan_kernel(const int* __restrict__ bcnt,
                                                    int* __restrict__ boff, int* __restrict__ cur,
                                                    int* __restrict__ row_off, int E, int N) {
    __shared__ int tmp[512];
    int t = threadIdx.x;
    int v = bcnt[t];
    tmp[t] = v;
    __syncthreads();
    for (int off = 1; off < 512; off <<= 1) {
        int u = (t >= off) ? tmp[t - off] : 0;
        __syncthreads();
        tmp[t] += u;
        __syncthreads();
    }
    int excl = tmp[t] - v;
    boff[t] = excl;
    cur[t] = excl;
    if (t == 511) boff[512] = tmp[511];   // == E
    if (t == 0) row_off[N] = E;
}

// ---------------- pass A: partition edges into buckets ----------------
__global__ __launch_bounds__(256) void passA_kernel(const int* __restrict__ src,
                                                    const int* __restrict__ dst,
                                                    const float* __restrict__ w,
                                                    int* __restrict__ cur,
                                                    int2* __restrict__ ebuf, int E) {
    __shared__ int h[512];
    __shared__ int bs[512];
    __shared__ int cl[512];
    int t = threadIdx.x;
    h[t] = 0; h[t + 256] = 0;
    __syncthreads();
    int chunk = (E + NBLKA - 1) / NBLKA;
    int beg = blockIdx.x * chunk;
    int end = min(beg + chunk, E);
    for (int e = beg + t; e < end; e += 256) atomicAdd(&h[dst[e] >> BSH], 1);
    __syncthreads();
#pragma unroll
    for (int q = 0; q < 2; ++q) {
        int i = t + q * 256;
        bs[i] = h[i] ? atomicAdd(&cur[i], h[i]) : 0;
        cl[i] = 0;
    }
    __syncthreads();
    for (int e = beg + t; e < end; e += 256) {
        int d = dst[e];
        int bk = d >> BSH;
        int r = atomicAdd(&cl[bk], 1);
        int low = d & ((1 << BSH) - 1);
        ebuf[bs[bk] + r] = make_int2(src[e] | (low << 20), __float_as_int(w[e]));
    }
}

// ---------------- pass B: in-LDS counting sort per bucket -> CSR + degrees ----------------
__global__ __launch_bounds__(256) void passB_kernel(const int* __restrict__ boff,
                                                    const int2* __restrict__ ebuf,
                                                    int* __restrict__ srcS, float* __restrict__ wS,
                                                    int* __restrict__ row_off,
                                                    float* __restrict__ dinv_w,
                                                    float* __restrict__ dinv_1, int N) {
    constexpr int BN = 1 << BSH;   // 128 nodes per bucket
    __shared__ int2 eb[BCAP];
    __shared__ int hist[BN];
    __shared__ int tmp[256];
    __shared__ int loc[BN];
    __shared__ int cur[BN];
    __shared__ float dws[BN];

    int b = blockIdx.x;
    int t = threadIdx.x;
    int base = boff[b];
    int sz = boff[b + 1] - base;

    if (t < BN) hist[t] = 0;
    __syncthreads();
    for (int i = t; i < sz; i += 256) {
        int2 e = ebuf[base + i];
        eb[i] = e;
        atomicAdd(&hist[((unsigned)e.x) >> 20], 1);
    }
    __syncthreads();
    tmp[t] = (t < BN) ? hist[t] : 0;
    __syncthreads();
    for (int off = 1; off < BN; off <<= 1) {
        int u = (t >= off && t < BN) ? tmp[t - off] : 0;
        __syncthreads();
        if (t < BN) tmp[t] += u;
        __syncthreads();
    }
    int node = (b << BSH) + t;
    if (t < BN) {
        loc[t] = tmp[t] - hist[t];
        cur[t] = 0;
        dws[t] = 0.0f;
        if (node < N) {
            row_off[node] = base + loc[t];
            dinv_1[node] = rsqrtf((float)hist[t] + 1.0f);
        }
    }
    __syncthreads();
    for (int i = t; i < sz; i += 256) {
        int key = eb[i].x;
        int bk = ((unsigned)key) >> 20;
        float wv = __int_as_float(eb[i].y);
        int r = atomicAdd(&cur[bk], 1);
        int slot = base + loc[bk] + r;
        srcS[slot] = key & 0xFFFFF;
        wS[slot] = wv;
        atomicAdd(&dws[bk], wv);
    }
    __syncthreads();
    if (t < BN && node < N) dinv_w[node] = rsqrtf(dws[t] + 1.0f);
}

// ---------------- packed coefficients per CSR row: pk = {src, coef} ----------------
__global__ void coef8_kernel(const int* __restrict__ row_off, const int* __restrict__ srcS,
                             const float* __restrict__ wS,
                             const float* __restrict__ dinv_w, const float* __restrict__ dinv_1,
                             int2* __restrict__ pkw, int2* __restrict__ pk1, int N) {
    int n = blockIdx.x * 16 + (threadIdx.x >> 4);   // 16 nodes/block, 16 lanes/node
    int l = threadIdx.x & 15;
    if (n >= N) return;
    int beg = row_off[n], end = row_off[n + 1];
    float dw = dinv_w[n], d1 = dinv_1[n];
    for (int j = beg + l; j < end; j += 16) {
        int s = srcS[j];
        pkw[j] = make_int2(s, __float_as_int(dinv_w[s] * wS[j] * dw));
        pk1[j] = make_int2(s, __float_as_int(dinv_1[s] * d1));
    }
}

// ---------------- W fragment pre-arrange for MFMA ----------------
template<int K, int DOUT>
__global__ __launch_bounds__(256) void arrangeW_kernel(const float* __restrict__ W,
                                                       _Float16* __restrict__ wf) {
    constexpr int KS = K / 32;
    constexpr int NFRAG = (DOUT / 16) * KS * 64;
    int fi = blockIdx.x * 256 + threadIdx.x;
    if (fi < NFRAG) {
        int l = fi & 63;
        int ks = (fi >> 6) % KS;
        int ct = fi / (64 * KS);
        _Float16* dstp = wf + fi * 8;
#pragma unroll
        for (int j = 0; j < 8; ++j) {
            int k = 32 * ks + 8 * (l >> 4) + j;
            int c = 16 * ct + (l & 15);
            dstp[j] = (_Float16)W[k * DOUT + c];
        }
    }
}

// ---------------- MFMA GEMM (XH=true only — replay-validated path) ----------------
template<int K, int DOUT, bool BIAS, bool HOUT>
__global__ __launch_bounds__(256) void mfma_gemm_kernel(const _Float16* __restrict__ X,
                                                        const _Float16* __restrict__ wf,
                                                        const float* __restrict__ b,
                                                        void* __restrict__ out, int N) {
    constexpr int KS = K / 32;
    constexpr int CT = DOUT / 16;
    int t = threadIdx.x;
    int w = t >> 6;
    int l = t & 63;
    int brow = blockIdx.x * 64;
    int rowA = brow + w * 16 + (l & 15);
    if (rowA > N - 1) rowA = N - 1;
    int koff = 8 * (l >> 4);

    f32x4 acc[CT];
#pragma unroll
    for (int ct = 0; ct < CT; ++ct) acc[ct] = (f32x4){0.f, 0.f, 0.f, 0.f};

#pragma unroll
    for (int ks = 0; ks < KS; ++ks) {
        f16x8 a = *reinterpret_cast<const f16x8*>(&X[rowA * K + 32 * ks + koff]);
#pragma unroll
        for (int ct = 0; ct < CT; ++ct) {
            f16x8 bf = *reinterpret_cast<const f16x8*>(&wf[((ct * KS + ks) * 64 + l) * 8]);
            acc[ct] = __builtin_amdgcn_mfma_f32_16x16x32_f16(a, bf, acc[ct], 0, 0, 0);
        }
    }

    int r0 = brow + w * 16 + 4 * (l >> 4);
    int cbase = l & 15;
#pragma unroll
    for (int ct = 0; ct < CT; ++ct) {
        int col = 16 * ct + cbase;
        float bb = 0.f;
        if constexpr (BIAS) bb = b[col];
#pragma unroll
        for (int q = 0; q < 4; ++q) {
            int row = r0 + q;
            if (row < N) {
                float v = acc[ct][q] + bb;
                if constexpr (HOUT) ((__half*)out)[row * DOUT + col] = __float2half_rn(v);
                else                ((float*)out)[row * DOUT + col] = v;
            }
        }
    }
}

// ---------------- simple register GEMM (small layers 2/3) ----------------
template<int K, int DOUT, bool BIAS, bool RELU_OUT, bool HOUT>
__global__ void gemm_kernel(const float* __restrict__ X, const float* __restrict__ W,
                            const float* __restrict__ b, void* __restrict__ Hout, int N) {
    constexpr int CG = DOUT / 4;
    constexpr int RPB = (256 / CG) * 4;
    int tx = threadIdx.x % CG;
    int ty = threadIdx.x / CG;
    int row0 = blockIdx.x * RPB + ty * 4;
    int col0 = tx * 4;

    float acc[4][4] = {};
    for (int k = 0; k < K; k += 4) {
        float4 w0 = *reinterpret_cast<const float4*>(&W[(k + 0) * DOUT + col0]);
        float4 w1 = *reinterpret_cast<const float4*>(&W[(k + 1) * DOUT + col0]);
        float4 w2 = *reinterpret_cast<const float4*>(&W[(k + 2) * DOUT + col0]);
        float4 w3 = *reinterpret_cast<const float4*>(&W[(k + 3) * DOUT + col0]);
#pragma unroll
        for (int r = 0; r < 4; ++r) {
            int row = row0 + r;
            if (row < N) {
                float4 x4 = *reinterpret_cast<const float4*>(&X[row * K + k]);
                acc[r][0] += x4.x * w0.x + x4.y * w1.x + x4.z * w2.x + x4.w * w3.x;
                acc[r][1] += x4.x * w0.y + x4.y * w1.y + x4.z * w2.y + x4.w * w3.y;
                acc[r][2] += x4.x * w0.z + x4.y * w1.z + x4.z * w2.z + x4.w * w3.z;
                acc[r][3] += x4.x * w0.w + x4.y * w1.w + x4.z * w2.w + x4.w * w3.w;
            }
        }
    }
    float4 bv = make_float4(0.f, 0.f, 0.f, 0.f);
    if constexpr (BIAS) bv = *reinterpret_cast<const float4*>(&b[col0]);
#pragma unroll
    for (int r = 0; r < 4; ++r) {
        int row = row0 + r;
        if (row < N) {
            float4 o = make_float4(acc[r][0] + bv.x, acc[r][1] + bv.y,
                                   acc[r][2] + bv.z, acc[r][3] + bv.w);
            if constexpr (RELU_OUT) {
                o.x = fmaxf(o.x, 0.f); o.y = fmaxf(o.y, 0.f);
                o.z = fmaxf(o.z, 0.f); o.w = fmaxf(o.w, 0.f);
            }
            if constexpr (HOUT) {
                *reinterpret_cast<short4*>(&((__half*)Hout)[row * DOUT + col0]) = f4_to_h4(o);
            } else {
                *reinterpret_cast<float4*>(&((float*)Hout)[row * DOUT + col0]) = o;
            }
        }
    }
}

// ---------------- pull aggregation (zero atomics, 8-wide, fp16 gathers, packed coef) ----------------
template<bool BIAS, bool RELU, bool HOUT>
__global__ void pull64_kernel(const int* __restrict__ row_off, const int2* __restrict__ pk,
                              const __half* __restrict__ H,
                              const float* __restrict__ dinv, const float* __restrict__ b,
                              void* __restrict__ out, int N) {
    int node = blockIdx.x * 4 + (threadIdx.x >> 6);
    int f = threadIdx.x & 63;
    if (node >= N) return;
    int beg = row_off[node], end = row_off[node + 1];
    float a0 = 0.f, a1 = 0.f, a2 = 0.f, a3 = 0.f, a4 = 0.f, a5 = 0.f, a6 = 0.f, a7 = 0.f;
    int j = beg;
    int end8 = beg + ((end - beg) & ~7);
    for (; j < end8; j += 8) {
        int2 e0 = pk[j+0], e1 = pk[j+1], e2 = pk[j+2], e3 = pk[j+3];
        int2 e4 = pk[j+4], e5 = pk[j+5], e6 = pk[j+6], e7 = pk[j+7];
        float h0 = __half2float(H[e0.x * 64 + f]), h1 = __half2float(H[e1.x * 64 + f]);
        float h2 = __half2float(H[e2.x * 64 + f]), h3 = __half2float(H[e3.x * 64 + f]);
        float h4 = __half2float(H[e4.x * 64 + f]), h5 = __half2float(H[e5.x * 64 + f]);
        float h6 = __half2float(H[e6.x * 64 + f]), h7 = __half2float(H[e7.x * 64 + f]);
        a0 += h0 * __int_as_float(e0.y); a1 += h1 * __int_as_float(e1.y);
        a2 += h2 * __int_as_float(e2.y); a3 += h3 * __int_as_float(e3.y);
        a4 += h4 * __int_as_float(e4.y); a5 += h5 * __int_as_float(e5.y);
        a6 += h6 * __int_as_float(e6.y); a7 += h7 * __int_as_float(e7.y);
    }
    int end4 = j + ((end - j) & ~3);
    for (; j < end4; j += 4) {
        int2 e0 = pk[j+0], e1 = pk[j+1], e2 = pk[j+2], e3 = pk[j+3];
        a0 += __half2float(H[e0.x * 64 + f]) * __int_as_float(e0.y);
        a1 += __half2float(H[e1.x * 64 + f]) * __int_as_float(e1.y);
        a2 += __half2float(H[e2.x * 64 + f]) * __int_as_float(e2.y);
        a3 += __half2float(H[e3.x * 64 + f]) * __int_as_float(e3.y);
    }
    for (; j < end; ++j) {
        int2 e = pk[j];
        a0 += __half2float(H[e.x * 64 + f]) * __int_as_float(e.y);
    }
    float acc = ((a0 + a1) + (a2 + a3)) + ((a4 + a5) + (a6 + a7));
    float di = dinv[node];
    float v = acc + __half2float(H[node * 64 + f]) * di * di;
    if constexpr (BIAS) v += b[f];
    if constexpr (RELU) v = fmaxf(v, 0.0f);
    if constexpr (HOUT) ((__half*)out)[node * 64 + f] = __float2half_rn(v);
    else                ((float*)out)[node * 64 + f] = v;
}

template<bool BIAS, bool RELU>
__global__ void pull32_kernel(const int* __restrict__ row_off, const int2* __restrict__ pk,
                              const __half* __restrict__ H,
                              const float* __restrict__ dinv, const float* __restrict__ b,
                              float* __restrict__ out, __half* __restrict__ out2h, int N) {
    int node = blockIdx.x * 8 + (threadIdx.x >> 5);
    int f = threadIdx.x & 31;
    if (node >= N) return;
    int beg = row_off[node], end = row_off[node + 1];
    float a0 = 0.f, a1 = 0.f, a2 = 0.f, a3 = 0.f, a4 = 0.f, a5 = 0.f, a6 = 0.f, a7 = 0.f;
    int j = beg;
    int end8 = beg + ((end - beg) & ~7);
    for (; j < end8; j += 8) {
        int2 e0 = pk[j+0], e1 = pk[j+1], e2 = pk[j+2], e3 = pk[j+3];
        int2 e4 = pk[j+4], e5 = pk[j+5], e6 = pk[j+6], e7 = pk[j+7];
        float h0 = __half2float(H[e0.x * 32 + f]), h1 = __half2float(H[e1.x * 32 + f]);
        float h2 = __half2float(H[e2.x * 32 + f]), h3 = __half2float(H[e3.x * 32 + f]);
        float h4 = __half2float(H[e4.x * 32 + f]), h5 = __half2float(H[e5.x * 32 + f]);
        float h6 = __half2float(H[e6.x * 32 + f]), h7 = __half2float(H[e7.x * 32 + f]);
        a0 += h0 * __int_as_float(e0.y); a1 += h1 * __int_as_float(e1.y);
        a2 += h2 * __int_as_float(e2.y); a3 += h3 * __int_as_float(e3.y);
        a4 += h4 * __int_as_float(e4.y); a5 += h5 * __int_as_float(e5.y);
        a6 += h6 * __int_as_float(e6.y); a7 += h7 * __int_as_float(e7.y);
    }
    int end4 = j + ((end - j) & ~3);
    for (; j < end4; j += 4) {
        int2 e0 = pk[j+0], e1 = pk[j+1], e2 = pk[j+2], e3 = pk[j+3];
        a0 += __half2float(H[e0.x * 32 + f]) * __int_as_float(e0.y);
        a1 += __half2float(H[e1.x * 32 + f]) * __int_as_float(e1.y);
        a2 += __half2float(H[e2.x * 32 + f]) * __int_as_float(e2.y);
        a3 += __half2float(H[e3.x * 32 + f]) * __int_as_float(e3.y);
    }
    for (; j < end; ++j) {
        int2 e = pk[j];
        a0 += __half2float(H[e.x * 32 + f]) * __int_as_float(e.y);
    }
    float acc = ((a0 + a1) + (a2 + a3)) + ((a4 + a5) + (a6 + a7));
    float di = dinv[node];
    float v = acc + __half2float(H[node * 32 + f]) * di * di;
    if constexpr (BIAS) v += b[f];
    if constexpr (RELU) v = fmaxf(v, 0.0f);
    out[node * 32 + f] = v;
    if (out2h) out2h[node * 32 + f] = __float2half_rn(v);
}

// ---------------- launch ----------------

extern "C" void kernel_launch(void* const* d_in, const int* in_sizes, int n_in,
                              void* d_out, int out_size, void* d_ws, size_t ws_size,
                              hipStream_t stream) {
    const float* x  = (const float*)d_in[0];
    const int*   ei = (const int*)d_in[1];
    const float* w  = (const float*)d_in[2];
    const float* W1 = (const float*)d_in[3];
    const float* b1 = (const float*)d_in[4];
    const float* W2 = (const float*)d_in[5];
    const float* b2 = (const float*)d_in[6];
    const float* W3 = (const float*)d_in[7];
    const float* b3 = (const float*)d_in[8];
    const float* W4 = (const float*)d_in[9];
    const float* b4 = (const float*)d_in[10];

    const int* src = ei;            // edge_index[0]
    const int* dst = ei + EE;       // edge_index[1]

    const int N = NN, E = EE;

    // workspace layout (4-byte words) — xh aliases [h1,g2h,zwsh,p3] (xh dead after L1 MFMA);
    // pk1 reuses ebuf (dead after passB). All other regions disjoint.
    float*    ws     = (float*)d_ws;
    float*    dinv_w = ws;                        // [0, 50176)
    float*    dinv_1 = ws + 50176;                // [50176, 100352)
    int*      row_off= (int*)(ws + 100352);       // [100352, 150528)
    int*      bcnt   = (int*)(ws + 150528);       // 512
    int*      boff   = (int*)(ws + 151040);       // 768
    int*      cur    = (int*)(ws + 151808);       // 512
    int2*     ebuf   = (int2*)(ws + 152320);      // [152320, 1752320)
    int2*     pk1    = ebuf;                      // reuse (ebuf dead after passB)
    int*      srcS   = (int*)(ws + 1752320);      // [1752320, 2552320)
    float*    wS     = ws + 2552320;              // [2552320, 3352320)
    int2*     pkw    = (int2*)(ws + 3352320);     // [3352320, 4952320)
    _Float16* wfrag4 = (_Float16*)(ws + 4952320); // [4952320, 4960512)
    _Float16* wfrag1 = (_Float16*)(ws + 4960512); // [4960512, 4968704)
    __half*   g1h    = (__half*)(ws + 4968704);   // N*64 half: [4968704, 6568704)
    __half*   xh     = (__half*)(ws + 6568704);   // N*256 half: [6568704, 12968704) (aliases below)
    float*    h1     = ws + 6568704;              // N*64 fp32
    __half*   g2h    = (__half*)(ws + 9768704);   // N*32 half
    __half*   zwsh   = (__half*)(ws + 10568704);  // N*32 half
    float*    p3     = ws + 11368704;             // N*32 fp32
    __half*   p4h    = (__half*)(ws + 12968704);  // N*64 half: [12968704, 14568704)
    __half*   dbufh  = g1h;                       // g1 dead after L1 pull

    float* recon = (float*)d_out;             // N*256
    float* zout  = (float*)d_out + NN * 256;  // N*32

    // ---- x -> fp16 + W fragment pre-arrange ----
    cvt_x_kernel<<<(N * 256 / 8 + 255) / 256, 256, 0, stream>>>(x, xh, N * 256 / 8);
    arrangeW_kernel<256, 64><<<8, 256, 0, stream>>>(W1, wfrag1);
    arrangeW_kernel<64, 256><<<8, 256, 0, stream>>>(W4, wfrag4);

    // ---- CSR build + normalization (two-level bucket sort) ----
    hipMemsetAsync(bcnt, 0, 512 * sizeof(int), stream);
    histb_kernel<<<NBLKA, 256, 0, stream>>>(dst, bcnt, E);
    bscan_kernel<<<1, 512, 0, stream>>>(bcnt, boff, cur, row_off, E, N);
    passA_kernel<<<NBLKA, 256, 0, stream>>>(src, dst, w, cur, ebuf, E);
    passB_kernel<<<NBUK, 256, 0, stream>>>(boff, ebuf, srcS, wS, row_off, dinv_w, dinv_1, N);
    coef8_kernel<<<(N + 15) / 16, 256, 0, stream>>>(row_off, srcS, wS, dinv_w, dinv_1,
                                                    pkw, pk1, N);

    // ---- layer 1: h1 = relu(prop_w(xh@W1) + b1)  [MFMA] ----
    mfma_gemm_kernel<256, 64, false, true><<<(N + 63) / 64, 256, 0, stream>>>((const _Float16*)xh, wfrag1, nullptr, (void*)g1h, N);
    pull64_kernel<true, true, false><<<(N + 3) / 4, 256, 0, stream>>>(row_off, pkw, g1h, dinv_w, b1, (void*)h1, N);

    // ---- layer 2: z = relu(prop_w(h1@W2) + b2) -> zout (fp32) + zwsh (half) ----
    gemm_kernel<64, 32, false, false, true><<<(N + 127) / 128, 256, 0, stream>>>(h1, W2, nullptr, (void*)g2h, N);
    pull32_kernel<true, true><<<(N + 7) / 8, 256, 0, stream>>>(row_off, pkw, g2h, dinv_w, b2, zout, zwsh, N);

    // ---- layer 3: d = relu(prop_w(z) @ W3 + b3)   (propagate in 32-dim space) ----
    pull32_kernel<false, false><<<(N + 7) / 8, 256, 0, stream>>>(row_off, pkw, zwsh, dinv_w, nullptr, p3, nullptr, N);
    gemm_kernel<32, 64, true, true, true><<<(N + 63) / 64, 256, 0, stream>>>(p3, W3, b3, (void*)dbufh, N);

    // ---- layer 4: recon = prop_1(d) @ W4 + b4   [MFMA] ----
    pull64_kernel<false, false, true><<<(N + 3) / 4, 256, 0, stream>>>(row_off, pk1, dbufh, dinv_1, nullptr, (void*)p4h, N);
    mfma_gemm_kernel<64, 256, true, false><<<(N + 63) / 64, 256, 0, stream>>>((const _Float16*)p4h, wfrag4, b4, (void*)recon, N);

    (void)in_sizes; (void)n_in; (void)out_size; (void)ws_size;
}

// Round 21
// 242.561 us; speedup vs baseline: 1.0262x; 1.0262x over previous
//
#include <hip/hip_runtime.h>
#include <hip/hip_fp16.h>

#define NN 50000
#define EE 800000
#define NP 50176        // padded N stride
#define BSH 7           // bucket shift: 128 nodes/bucket
#define NBUK 391        // ((NN-1)>>BSH)+1
#define BCAP 4096       // max edges per bucket held in LDS
#define NBLKA 128       // blocks for hist/partition passes

using f16x8 = __attribute__((ext_vector_type(8))) _Float16;
using f32x4 = __attribute__((ext_vector_type(4))) float;

__device__ inline short4 f4_to_h4(float4 o) {
    union { __half h[4]; short4 s; } u;
    u.h[0] = __float2half_rn(o.x); u.h[1] = __float2half_rn(o.y);
    u.h[2] = __float2half_rn(o.z); u.h[3] = __float2half_rn(o.w);
    return u.s;
}

// ---------------- x fp32 -> fp16 (vectorized, 8/thread) ----------------
__global__ __launch_bounds__(256) void cvt_x_kernel(const float* __restrict__ x,
                                                    __half* __restrict__ xh, int n8) {
    int i = blockIdx.x * 256 + threadIdx.x;
    if (i < n8) {
        float4 v0 = reinterpret_cast<const float4*>(x)[i * 2];
        float4 v1 = reinterpret_cast<const float4*>(x)[i * 2 + 1];
        short4 h0 = f4_to_h4(v0);
        short4 h1 = f4_to_h4(v1);
        reinterpret_cast<short4*>(xh)[i * 2] = h0;
        reinterpret_cast<short4*>(xh)[i * 2 + 1] = h1;
    }
}

// ---------------- bucket histogram (LDS-aggregated) ----------------
__global__ __launch_bounds__(256) void histb_kernel(const int* __restrict__ dst,
                                                    int* __restrict__ bcnt, int E) {
    __shared__ int h[512];
    int t = threadIdx.x;
    h[t] = 0; h[t + 256] = 0;
    __syncthreads();
    int chunk = (E + NBLKA - 1) / NBLKA;
    int beg = blockIdx.x * chunk;
    int end = min(beg + chunk, E);
    for (int e = beg + t; e < end; e += 256) atomicAdd(&h[dst[e] >> BSH], 1);
    __syncthreads();
    if (h[t]) atomicAdd(&bcnt[t], h[t]);
    if (h[t + 256]) atomicAdd(&bcnt[t + 256], h[t + 256]);
}

// ---------------- bucket offset scan (single block, 512 threads) ----------------
__global__ __launch_bounds__(512) void bscan_kernel(const int* __restrict__ bcnt,
                                                    int* __restrict__ boff, int* __restrict__ cur,
                                                    int* __restrict__ row_off, int E, int N) {
    __shared__ int tmp[512];
    int t = threadIdx.x;
    int v = bcnt[t];
    tmp[t] = v;
    __syncthreads();
    for (int off = 1; off < 512; off <<= 1) {
        int u = (t >= off) ? tmp[t - off] : 0;
        __syncthreads();
        tmp[t] += u;
        __syncthreads();
    }
    int excl = tmp[t] - v;
    boff[t] = excl;
    cur[t] = excl;
    if (t == 511) boff[512] = tmp[511];   // == E
    if (t == 0) row_off[N] = E;
}

// ---------------- pass A: partition edges into buckets ----------------
__global__ __launch_bounds__(256) void passA_kernel(const int* __restrict__ src,
                                                    const int* __restrict__ dst,
                                                    const float* __restrict__ w,
                                                    int* __restrict__ cur,
                                                    int2* __restrict__ ebuf, int E) {
    __shared__ int h[512];
    __shared__ int bs[512];
    __shared__ int cl[512];
    int t = threadIdx.x;
    h[t] = 0; h[t + 256] = 0;
    __syncthreads();
    int chunk = (E + NBLKA - 1) / NBLKA;
    int beg = blockIdx.x * chunk;
    int end = min(beg + chunk, E);
    for (int e = beg + t; e < end; e += 256) atomicAdd(&h[dst[e] >> BSH], 1);
    __syncthreads();
#pragma unroll
    for (int q = 0; q < 2; ++q) {
        int i = t + q * 256;
        bs[i] = h[i] ? atomicAdd(&cur[i], h[i]) : 0;
        cl[i] = 0;
    }
    __syncthreads();
    for (int e = beg + t; e < end; e += 256) {
        int d = dst[e];
        int bk = d >> BSH;
        int r = atomicAdd(&cl[bk], 1);
        int low = d & ((1 << BSH) - 1);
        ebuf[bs[bk] + r] = make_int2(src[e] | (low << 20), __float_as_int(w[e]));
    }
}

// ---------------- pass B: in-LDS counting sort per bucket -> CSR + degrees ----------------
__global__ __launch_bounds__(256) void passB_kernel(const int* __restrict__ boff,
                                                    const int2* __restrict__ ebuf,
                                                    int* __restrict__ srcS, float* __restrict__ wS,
                                                    int* __restrict__ row_off,
                                                    float* __restrict__ dinv_w,
                                                    float* __restrict__ dinv_1, int N) {
    constexpr int BN = 1 << BSH;   // 128 nodes per bucket
    __shared__ int2 eb[BCAP];
    __shared__ int hist[BN];
    __shared__ int tmp[256];
    __shared__ int loc[BN];
    __shared__ int cur[BN];
    __shared__ float dws[BN];

    int b = blockIdx.x;
    int t = threadIdx.x;
    int base = boff[b];
    int sz = boff[b + 1] - base;

    if (t < BN) hist[t] = 0;
    __syncthreads();
    for (int i = t; i < sz; i += 256) {
        int2 e = ebuf[base + i];
        eb[i] = e;
        atomicAdd(&hist[((unsigned)e.x) >> 20], 1);
    }
    __syncthreads();
    tmp[t] = (t < BN) ? hist[t] : 0;
    __syncthreads();
    for (int off = 1; off < BN; off <<= 1) {
        int u = (t >= off && t < BN) ? tmp[t - off] : 0;
        __syncthreads();
        if (t < BN) tmp[t] += u;
        __syncthreads();
    }
    int node = (b << BSH) + t;
    if (t < BN) {
        loc[t] = tmp[t] - hist[t];
        cur[t] = 0;
        dws[t] = 0.0f;
        if (node < N) {
            row_off[node] = base + loc[t];
            dinv_1[node] = rsqrtf((float)hist[t] + 1.0f);
        }
    }
    __syncthreads();
    for (int i = t; i < sz; i += 256) {
        int key = eb[i].x;
        int bk = ((unsigned)key) >> 20;
        float wv = __int_as_float(eb[i].y);
        int r = atomicAdd(&cur[bk], 1);
        int slot = base + loc[bk] + r;
        srcS[slot] = key & 0xFFFFF;
        wS[slot] = wv;
        atomicAdd(&dws[bk], wv);
    }
    __syncthreads();
    if (t < BN && node < N) dinv_w[node] = rsqrtf(dws[t] + 1.0f);
}

// ---------------- coefficients per CSR row ----------------
__global__ void coef8_kernel(const int* __restrict__ row_off, const int* __restrict__ srcS,
                             const float* __restrict__ wS,
                             const float* __restrict__ dinv_w, const float* __restrict__ dinv_1,
                             float* __restrict__ coefwS, float* __restrict__ coef1S, int N) {
    int n = blockIdx.x * 16 + (threadIdx.x >> 4);   // 16 nodes/block, 16 lanes/node
    int l = threadIdx.x & 15;
    if (n >= N) return;
    int beg = row_off[n], end = row_off[n + 1];
    float dw = dinv_w[n], d1 = dinv_1[n];
    for (int j = beg + l; j < end; j += 16) {
        int s = srcS[j];
        coefwS[j] = dinv_w[s] * wS[j] * dw;
        coef1S[j] = dinv_1[s] * d1;
    }
}

// ---------------- W fragment pre-arrange for MFMA ----------------
template<int K, int DOUT>
__global__ __launch_bounds__(256) void arrangeW_kernel(const float* __restrict__ W,
                                                       _Float16* __restrict__ wf) {
    constexpr int KS = K / 32;
    constexpr int NFRAG = (DOUT / 16) * KS * 64;
    int fi = blockIdx.x * 256 + threadIdx.x;
    if (fi < NFRAG) {
        int l = fi & 63;
        int ks = (fi >> 6) % KS;
        int ct = fi / (64 * KS);
        _Float16* dstp = wf + fi * 8;
#pragma unroll
        for (int j = 0; j < 8; ++j) {
            int k = 32 * ks + 8 * (l >> 4) + j;
            int c = 16 * ct + (l & 15);
            dstp[j] = (_Float16)W[k * DOUT + c];
        }
    }
}

// ---------------- MFMA GEMM (XH=true only — replay-validated path) ----------------
// out = X @ W (+bias), wave = 16 rows x DOUT cols
template<int K, int DOUT, bool BIAS, bool HOUT>
__global__ __launch_bounds__(256) void mfma_gemm_kernel(const _Float16* __restrict__ X,
                                                        const _Float16* __restrict__ wf,
                                                        const float* __restrict__ b,
                                                        void* __restrict__ out, int N) {
    constexpr int KS = K / 32;
    constexpr int CT = DOUT / 16;
    int t = threadIdx.x;
    int w = t >> 6;
    int l = t & 63;
    int brow = blockIdx.x * 64;
    int rowA = brow + w * 16 + (l & 15);
    if (rowA > N - 1) rowA = N - 1;
    int koff = 8 * (l >> 4);

    f32x4 acc[CT];
#pragma unroll
    for (int ct = 0; ct < CT; ++ct) acc[ct] = (f32x4){0.f, 0.f, 0.f, 0.f};

#pragma unroll
    for (int ks = 0; ks < KS; ++ks) {
        f16x8 a = *reinterpret_cast<const f16x8*>(&X[rowA * K + 32 * ks + koff]);
#pragma unroll
        for (int ct = 0; ct < CT; ++ct) {
            f16x8 bf = *reinterpret_cast<const f16x8*>(&wf[((ct * KS + ks) * 64 + l) * 8]);
            acc[ct] = __builtin_amdgcn_mfma_f32_16x16x32_f16(a, bf, acc[ct], 0, 0, 0);
        }
    }

    int r0 = brow + w * 16 + 4 * (l >> 4);
    int cbase = l & 15;
#pragma unroll
    for (int ct = 0; ct < CT; ++ct) {
        int col = 16 * ct + cbase;
        float bb = 0.f;
        if constexpr (BIAS) bb = b[col];
#pragma unroll
        for (int q = 0; q < 4; ++q) {
            int row = r0 + q;
            if (row < N) {
                float v = acc[ct][q] + bb;
                if constexpr (HOUT) ((__half*)out)[row * DOUT + col] = __float2half_rn(v);
                else                ((float*)out)[row * DOUT + col] = v;
            }
        }
    }
}

// ---------------- simple register GEMM (small layers 2/3) ----------------
template<int K, int DOUT, bool BIAS, bool RELU_OUT, bool HOUT>
__global__ void gemm_kernel(const float* __restrict__ X, const float* __restrict__ W,
                            const float* __restrict__ b, void* __restrict__ Hout, int N) {
    constexpr int CG = DOUT / 4;
    constexpr int RPB = (256 / CG) * 4;
    int tx = threadIdx.x % CG;
    int ty = threadIdx.x / CG;
    int row0 = blockIdx.x * RPB + ty * 4;
    int col0 = tx * 4;

    float acc[4][4] = {};
    for (int k = 0; k < K; k += 4) {
        float4 w0 = *reinterpret_cast<const float4*>(&W[(k + 0) * DOUT + col0]);
        float4 w1 = *reinterpret_cast<const float4*>(&W[(k + 1) * DOUT + col0]);
        float4 w2 = *reinterpret_cast<const float4*>(&W[(k + 2) * DOUT + col0]);
        float4 w3 = *reinterpret_cast<const float4*>(&W[(k + 3) * DOUT + col0]);
#pragma unroll
        for (int r = 0; r < 4; ++r) {
            int row = row0 + r;
            if (row < N) {
                float4 x4 = *reinterpret_cast<const float4*>(&X[row * K + k]);
                acc[r][0] += x4.x * w0.x + x4.y * w1.x + x4.z * w2.x + x4.w * w3.x;
                acc[r][1] += x4.x * w0.y + x4.y * w1.y + x4.z * w2.y + x4.w * w3.y;
                acc[r][2] += x4.x * w0.z + x4.y * w1.z + x4.z * w2.z + x4.w * w3.z;
                acc[r][3] += x4.x * w0.w + x4.y * w1.w + x4.z * w2.w + x4.w * w3.w;
            }
        }
    }
    float4 bv = make_float4(0.f, 0.f, 0.f, 0.f);
    if constexpr (BIAS) bv = *reinterpret_cast<const float4*>(&b[col0]);
#pragma unroll
    for (int r = 0; r < 4; ++r) {
        int row = row0 + r;
        if (row < N) {
            float4 o = make_float4(acc[r][0] + bv.x, acc[r][1] + bv.y,
                                   acc[r][2] + bv.z, acc[r][3] + bv.w);
            if constexpr (RELU_OUT) {
                o.x = fmaxf(o.x, 0.f); o.y = fmaxf(o.y, 0.f);
                o.z = fmaxf(o.z, 0.f); o.w = fmaxf(o.w, 0.f);
            }
            if constexpr (HOUT) {
                *reinterpret_cast<short4*>(&((__half*)Hout)[row * DOUT + col0]) = f4_to_h4(o);
            } else {
                *reinterpret_cast<float4*>(&((float*)Hout)[row * DOUT + col0]) = o;
            }
        }
    }
}

// ---------------- pull aggregation (zero atomics, 8-wide, fp16 gathers) ----------------
template<bool BIAS, bool RELU, bool HOUT>
__global__ void pull64_kernel(const int* __restrict__ row_off, const int* __restrict__ srcS,
                              const float* __restrict__ coefS, const __half* __restrict__ H,
                              const float* __restrict__ dinv, const float* __restrict__ b,
                              void* __restrict__ out, int N) {
    int node = blockIdx.x * 4 + (threadIdx.x >> 6);
    int f = threadIdx.x & 63;
    if (node >= N) return;
    int beg = row_off[node], end = row_off[node + 1];
    float a0 = 0.f, a1 = 0.f, a2 = 0.f, a3 = 0.f, a4 = 0.f, a5 = 0.f, a6 = 0.f, a7 = 0.f;
    int j = beg;
    int end8 = beg + ((end - beg) & ~7);
    for (; j < end8; j += 8) {
        int s0 = srcS[j+0], s1 = srcS[j+1], s2 = srcS[j+2], s3 = srcS[j+3];
        int s4 = srcS[j+4], s5 = srcS[j+5], s6 = srcS[j+6], s7 = srcS[j+7];
        float c0 = coefS[j+0], c1 = coefS[j+1], c2 = coefS[j+2], c3 = coefS[j+3];
        float c4 = coefS[j+4], c5 = coefS[j+5], c6 = coefS[j+6], c7 = coefS[j+7];
        float h0 = __half2float(H[s0 * 64 + f]), h1 = __half2float(H[s1 * 64 + f]);
        float h2 = __half2float(H[s2 * 64 + f]), h3 = __half2float(H[s3 * 64 + f]);
        float h4 = __half2float(H[s4 * 64 + f]), h5 = __half2float(H[s5 * 64 + f]);
        float h6 = __half2float(H[s6 * 64 + f]), h7 = __half2float(H[s7 * 64 + f]);
        a0 += h0 * c0; a1 += h1 * c1; a2 += h2 * c2; a3 += h3 * c3;
        a4 += h4 * c4; a5 += h5 * c5; a6 += h6 * c6; a7 += h7 * c7;
    }
    int end4 = j + ((end - j) & ~3);
    for (; j < end4; j += 4) {
        int s0 = srcS[j+0], s1 = srcS[j+1], s2 = srcS[j+2], s3 = srcS[j+3];
        float c0 = coefS[j+0], c1 = coefS[j+1], c2 = coefS[j+2], c3 = coefS[j+3];
        a0 += __half2float(H[s0 * 64 + f]) * c0; a1 += __half2float(H[s1 * 64 + f]) * c1;
        a2 += __half2float(H[s2 * 64 + f]) * c2; a3 += __half2float(H[s3 * 64 + f]) * c3;
    }
    for (; j < end; ++j) a0 += __half2float(H[srcS[j] * 64 + f]) * coefS[j];
    float acc = ((a0 + a1) + (a2 + a3)) + ((a4 + a5) + (a6 + a7));
    float di = dinv[node];
    float v = acc + __half2float(H[node * 64 + f]) * di * di;
    if constexpr (BIAS) v += b[f];
    if constexpr (RELU) v = fmaxf(v, 0.0f);
    if constexpr (HOUT) ((__half*)out)[node * 64 + f] = __float2half_rn(v);
    else                ((float*)out)[node * 64 + f] = v;
}

template<bool BIAS, bool RELU>
__global__ void pull32_kernel(const int* __restrict__ row_off, const int* __restrict__ srcS,
                              const float* __restrict__ coefS, const __half* __restrict__ H,
                              const float* __restrict__ dinv, const float* __restrict__ b,
                              float* __restrict__ out, __half* __restrict__ out2h, int N) {
    int node = blockIdx.x * 8 + (threadIdx.x >> 5);
    int f = threadIdx.x & 31;
    if (node >= N) return;
    int beg = row_off[node], end = row_off[node + 1];
    float a0 = 0.f, a1 = 0.f, a2 = 0.f, a3 = 0.f, a4 = 0.f, a5 = 0.f, a6 = 0.f, a7 = 0.f;
    int j = beg;
    int end8 = beg + ((end - beg) & ~7);
    for (; j < end8; j += 8) {
        int s0 = srcS[j+0], s1 = srcS[j+1], s2 = srcS[j+2], s3 = srcS[j+3];
        int s4 = srcS[j+4], s5 = srcS[j+5], s6 = srcS[j+6], s7 = srcS[j+7];
        float c0 = coefS[j+0], c1 = coefS[j+1], c2 = coefS[j+2], c3 = coefS[j+3];
        float c4 = coefS[j+4], c5 = coefS[j+5], c6 = coefS[j+6], c7 = coefS[j+7];
        float h0 = __half2float(H[s0 * 32 + f]), h1 = __half2float(H[s1 * 32 + f]);
        float h2 = __half2float(H[s2 * 32 + f]), h3 = __half2float(H[s3 * 32 + f]);
        float h4 = __half2float(H[s4 * 32 + f]), h5 = __half2float(H[s5 * 32 + f]);
        float h6 = __half2float(H[s6 * 32 + f]), h7 = __half2float(H[s7 * 32 + f]);
        a0 += h0 * c0; a1 += h1 * c1; a2 += h2 * c2; a3 += h3 * c3;
        a4 += h4 * c4; a5 += h5 * c5; a6 += h6 * c6; a7 += h7 * c7;
    }
    int end4 = j + ((end - j) & ~3);
    for (; j < end4; j += 4) {
        int s0 = srcS[j+0], s1 = srcS[j+1], s2 = srcS[j+2], s3 = srcS[j+3];
        float c0 = coefS[j+0], c1 = coefS[j+1], c2 = coefS[j+2], c3 = coefS[j+3];
        a0 += __half2float(H[s0 * 32 + f]) * c0; a1 += __half2float(H[s1 * 32 + f]) * c1;
        a2 += __half2float(H[s2 * 32 + f]) * c2; a3 += __half2float(H[s3 * 32 + f]) * c3;
    }
    for (; j < end; ++j) a0 += __half2float(H[srcS[j] * 32 + f]) * coefS[j];
    float acc = ((a0 + a1) + (a2 + a3)) + ((a4 + a5) + (a6 + a7));
    float di = dinv[node];
    float v = acc + __half2float(H[node * 32 + f]) * di * di;
    if constexpr (BIAS) v += b[f];
    if constexpr (RELU) v = fmaxf(v, 0.0f);
    out[node * 32 + f] = v;
    if (out2h) out2h[node * 32 + f] = __float2half_rn(v);
}

// ---------------- launch ----------------

extern "C" void kernel_launch(void* const* d_in, const int* in_sizes, int n_in,
                              void* d_out, int out_size, void* d_ws, size_t ws_size,
                              hipStream_t stream) {
    const float* x  = (const float*)d_in[0];
    const int*   ei = (const int*)d_in[1];
    const float* w  = (const float*)d_in[2];
    const float* W1 = (const float*)d_in[3];
    const float* b1 = (const float*)d_in[4];
    const float* W2 = (const float*)d_in[5];
    const float* b2 = (const float*)d_in[6];
    const float* W3 = (const float*)d_in[7];
    const float* b3 = (const float*)d_in[8];
    const float* W4 = (const float*)d_in[9];
    const float* b4 = (const float*)d_in[10];

    const int* src = ei;            // edge_index[0]
    const int* dst = ei + EE;       // edge_index[1]

    const int N = NN, E = EE;

    // workspace layout (4-byte words) — xh ALIASES [h1,g2h,zwsh,p3]:
    // xh live only [cvt_x .. mfma L1]; h1/g2h/zwsh/p3 all written after that.
    float*    ws     = (float*)d_ws;
    float*    dinv_w = ws;                        // [0, 50176)
    float*    dinv_1 = ws + 50176;                // [50176, 100352)
    int*      row_off= (int*)(ws + 100352);       // [100352, 150528)
    int*      bcnt   = (int*)(ws + 150528);       // 512
    int*      boff   = (int*)(ws + 151040);       // 768
    int*      cur    = (int*)(ws + 151808);       // 512
    int2*     ebuf   = (int2*)(ws + 152320);      // [152320, 1752320)
    int*      srcS   = (int*)(ws + 1752320);      // [1752320, 2552320)
    float*    wS     = ws + 2552320;              // [2552320, 3352320)
    float*    coefwS = ws + 3352320;              // [3352320, 4152320)
    float*    coef1S = ws + 4152320;              // [4152320, 4952320)
    _Float16* wfrag4 = (_Float16*)(ws + 4952320); // [4952320, 4960512)
    _Float16* wfrag1 = (_Float16*)(ws + 4960512); // [4960512, 4968704)
    __half*   g1h    = (__half*)(ws + 4968704);   // N*64 half: [4968704, 6568704)
    __half*   xh     = (__half*)(ws + 6568704);   // N*256 half: [6568704, 12968704)  (aliases below)
    float*    h1     = ws + 6568704;              // N*64 fp32: [6568704, 9768704)
    __half*   g2h    = (__half*)(ws + 9768704);   // N*32 half: [9768704, 10568704)
    __half*   zwsh   = (__half*)(ws + 10568704);  // N*32 half: [10568704, 11368704)
    float*    p3     = ws + 11368704;             // N*32 fp32: [11368704, 12968704)
    __half*   p4h    = (__half*)(ws + 12968704);  // N*64 half: [12968704, 14568704)
    __half*   dbufh  = g1h;                       // g1 dead after L1 pull

    float* recon = (float*)d_out;             // N*256
    float* zout  = (float*)d_out + NN * 256;  // N*32

    // ---- x -> fp16 + W fragment pre-arrange ----
    cvt_x_kernel<<<(N * 256 / 8 + 255) / 256, 256, 0, stream>>>(x, xh, N * 256 / 8);
    arrangeW_kernel<256, 64><<<8, 256, 0, stream>>>(W1, wfrag1);
    arrangeW_kernel<64, 256><<<8, 256, 0, stream>>>(W4, wfrag4);

    // ---- CSR build + normalization (two-level bucket sort) ----
    hipMemsetAsync(bcnt, 0, 512 * sizeof(int), stream);
    histb_kernel<<<NBLKA, 256, 0, stream>>>(dst, bcnt, E);
    bscan_kernel<<<1, 512, 0, stream>>>(bcnt, boff, cur, row_off, E, N);
    passA_kernel<<<NBLKA, 256, 0, stream>>>(src, dst, w, cur, ebuf, E);
    passB_kernel<<<NBUK, 256, 0, stream>>>(boff, ebuf, srcS, wS, row_off, dinv_w, dinv_1, N);
    coef8_kernel<<<(N + 15) / 16, 256, 0, stream>>>(row_off, srcS, wS, dinv_w, dinv_1,
                                                    coefwS, coef1S, N);

    // ---- layer 1: h1 = relu(prop_w(xh@W1) + b1)  [MFMA, XH=true path] ----
    mfma_gemm_kernel<256, 64, false, true><<<(N + 63) / 64, 256, 0, stream>>>((const _Float16*)xh, wfrag1, nullptr, (void*)g1h, N);
    pull64_kernel<true, true, false><<<(N + 3) / 4, 256, 0, stream>>>(row_off, srcS, coefwS, g1h, dinv_w, b1, (void*)h1, N);

    // ---- layer 2: z = relu(prop_w(h1@W2) + b2) -> zout (fp32) + zwsh (half) ----
    gemm_kernel<64, 32, false, false, true><<<(N + 127) / 128, 256, 0, stream>>>(h1, W2, nullptr, (void*)g2h, N);
    pull32_kernel<true, true><<<(N + 7) / 8, 256, 0, stream>>>(row_off, srcS, coefwS, g2h, dinv_w, b2, zout, zwsh, N);

    // ---- layer 3: d = relu(prop_w(z) @ W3 + b3)   (propagate in 32-dim space) ----
    pull32_kernel<false, false><<<(N + 7) / 8, 256, 0, stream>>>(row_off, srcS, coefwS, zwsh, dinv_w, nullptr, p3, nullptr, N);
    gemm_kernel<32, 64, true, true, true><<<(N + 63) / 64, 256, 0, stream>>>(p3, W3, b3, (void*)dbufh, N);

    // ---- layer 4: recon = prop_1(d) @ W4 + b4   [MFMA, XH=true path] ----
    pull64_kernel<false, false, true><<<(N + 3) / 4, 256, 0, stream>>>(row_off, srcS, coef1S, dbufh, dinv_1, nullptr, (void*)p4h, N);
    mfma_gemm_kernel<64, 256, true, false><<<(N + 63) / 64, 256, 0, stream>>>((const _Float16*)p4h, wfrag4, b4, (void*)recon, N);

    (void)in_sizes; (void)n_in; (void)out_size; (void)ws_size;
}